// Round 3
// baseline (1057.769 us; speedup 1.0000x reference)
//
#include <hip/hip_runtime.h>

#define NORI 8
#define KS 7
#define CH 32
#define IMG 224
#define STRIP 16           // output rows per block
#define SROWS (STRIP + 6)  // staged input rows (halo 3 top+bottom)
#define PITCH 232          // floats per staged row; col j holds x = j-4

// load a staged row's 12-float window for this lane (3x ds_read_b128, wave-uniform row)
#define LOAD_ROW(dst, rowidx) do { \
    const float4* p_ = (const float4*)&s_in[(rowidx) * PITCH + 4 * l]; \
    float4 u0 = p_[0], u1 = p_[1], u2 = p_[2]; \
    dst[0]=u0.x; dst[1]=u0.y; dst[2]=u0.z;  dst[3]=u0.w; \
    dst[4]=u1.x; dst[5]=u1.y; dst[6]=u1.z;  dst[7]=u1.w; \
    dst[8]=u2.x; dst[9]=u2.y; dst[10]=u2.z; dst[11]=u2.w; } while(0)

__global__ __launch_bounds__(256, 3)
void gabor_dw_conv(const float* __restrict__ x, const float* __restrict__ filt,
                   float* __restrict__ out) {
    __shared__ __align__(16) float s_in[SROWS * PITCH];   // 22*232*4 = 20416 B

    // ---- bijective XCD swizzle: nwg = 14*32*16 = 7168 = 8 * 896 ----
    const int cpx = (14 * CH * 16) / 8;
    int bid = blockIdx.x;
    int logical = (bid & 7) * cpx + (bid >> 3);
    const int strip = logical % 14;
    const int plane = logical / 14;          // 0..511
    const int c = plane & (CH - 1);
    const int b = plane >> 5;
    const int gy0 = strip * STRIP;

    const int tid = threadIdx.x;
    const int wv  = tid >> 6;                // wave 0..3
    const int l   = tid & 63;

    // ---- stage input strip: rows gy0-3 .. gy0+18; s_in col j = x (j-4) ----
    // lane l loads aligned float4 of x-cols 4(l-1)..4(l-1)+3 -> LDS cols 4l..4l+3
    const float* xp = x + (size_t)(b * CH + c) * (IMG * IMG);
    {
        const int gxw = l - 1;               // float4 index within global row
        const bool xok = (gxw >= 0) && (gxw < IMG / 4);
        for (int row = wv; row < SROWS; row += 4) {
            int gy = gy0 - 3 + row;
            float4 v = make_float4(0.f, 0.f, 0.f, 0.f);
            if (xok && gy >= 0 && gy < IMG)
                v = *(const float4*)(xp + gy * IMG + 4 * gxw);
            if (l < 58)
                *(float4*)&s_in[row * PITCH + 4 * l] = v;
        }
    }

    // ---- hoist this wave's 2 orientations' weights into VGPRs ----
    const int o0 = 2 * wv, o1 = o0 + 1;
    float w0[49], w1[49];
    {
        const float* f0 = filt + (size_t)(c * NORI + o0) * 49;
        const float* f1 = f0 + 49;
        #pragma unroll
        for (int k = 0; k < 49; ++k) { w0[k] = f0[k]; w1[k] = f1[k]; }
    }

    __syncthreads();
    if (l >= 56) return;                     // 56 lanes x 4 px = 224 row width

    const int x0 = 4 * l;
    float* op0 = out + ((size_t)(b * (CH * NORI) + c * NORI + o0) * IMG + gy0) * IMG + x0;
    float* op1 = op0 + (size_t)IMG * IMG;    // o1 plane

    // ---- compute: every wave does all 16 rows for its 2 orientations ----
    for (int it = 0; it < STRIP / 2; ++it) {
        const int r0 = 2 * it;
        float a00[4] = {0,0,0,0}, a01[4] = {0,0,0,0};   // row r0,  ori o0/o1
        float a10[4] = {0,0,0,0}, a11[4] = {0,0,0,0};   // row r0+1
        float RA[12], RB[12];
        LOAD_ROW(RA, r0);                     // in-row r0 (= r0+ky at ky=0)
        #pragma unroll
        for (int ky = 0; ky < KS; ++ky) {
            LOAD_ROW(RB, r0 + 1 + ky);        // in-row for out-row r0+1 at this ky
            #pragma unroll
            for (int kx = 0; kx < KS; ++kx) {
                const float c0 = w0[ky * 7 + kx];
                const float c1 = w1[ky * 7 + kx];
                #pragma unroll
                for (int p = 0; p < 4; ++p) {
                    // out x = x0+p, tap kx -> input x = x0+p+kx-3 -> col j = p+kx+1
                    a00[p] += RA[p + kx + 1] * c0;
                    a01[p] += RA[p + kx + 1] * c1;
                    a10[p] += RB[p + kx + 1] * c0;
                    a11[p] += RB[p + kx + 1] * c1;
                }
            }
            #pragma unroll
            for (int j = 0; j < 12; ++j) RA[j] = RB[j];   // rotate window
        }
        *(float4*)(op0 + (size_t)r0 * IMG)       = make_float4(a00[0], a00[1], a00[2], a00[3]);
        *(float4*)(op0 + (size_t)(r0 + 1) * IMG) = make_float4(a10[0], a10[1], a10[2], a10[3]);
        *(float4*)(op1 + (size_t)r0 * IMG)       = make_float4(a01[0], a01[1], a01[2], a01[3]);
        *(float4*)(op1 + (size_t)(r0 + 1) * IMG) = make_float4(a11[0], a11[1], a11[2], a11[3]);
    }
}

extern "C" void kernel_launch(void* const* d_in, const int* in_sizes, int n_in,
                              void* d_out, int out_size, void* d_ws, size_t ws_size,
                              hipStream_t stream) {
    const float* x = (const float*)d_in[0];
    const float* filt = (const float*)d_in[1];
    float* out = (float*)d_out;

    dim3 grid(14 * CH * 16);   // y-strips * channels * batch = 7168
    dim3 block(256);
    gabor_dw_conv<<<grid, block, 0, stream>>>(x, filt, out);
}

// Round 4
// 323.173 us; speedup vs baseline: 3.2731x; 3.2731x over previous
//
#include <hip/hip_runtime.h>

#define NORI 8
#define KS 7
#define CH 32
#define IMG 224
#define STRIP 16           // output rows per block
#define SROWS (STRIP + 6)  // staged input rows (halo 3 top+bottom) = 22
#define PITCH 232          // floats per staged row; col j holds x-col (j-4)

typedef float f4 __attribute__((ext_vector_type(4)));

// read the 12-float window of staged row `rowidx` for lane `l` into 12 scalars
#define READ_WIN(dst, rowidx) do {                                         \
    const f4* p_ = (const f4*)&s_in[(rowidx) * PITCH + 4 * l];             \
    f4 u0 = p_[0], u1 = p_[1], u2 = p_[2];                                 \
    dst[0]=u0.x; dst[1]=u0.y; dst[2]=u0.z;  dst[3]=u0.w;                   \
    dst[4]=u1.x; dst[5]=u1.y; dst[6]=u1.z;  dst[7]=u1.w;                   \
    dst[8]=u2.x; dst[9]=u2.y; dst[10]=u2.z; dst[11]=u2.w; } while (0)

__global__ __launch_bounds__(512, 4)   // 2 blocks/CU, VGPR cap 128
void gabor_dw_conv(const float* __restrict__ x, const float* __restrict__ filt,
                   float* __restrict__ out) {
    __shared__ __align__(16) float s_in[SROWS * PITCH];   // 20416 B

    // bijective XCD swizzle: nwg = 14*32*16 = 7168 = 8 * 896 exactly
    const int cpx = (14 * CH * 16) / 8;          // 896
    const int bid = blockIdx.x;
    const int logical = (bid & 7) * cpx + (bid >> 3);
    const int strip = logical % 14;
    const int plane = logical / 14;              // 0..511
    const int c = plane & (CH - 1);
    const int b = plane >> 5;
    const int gy0 = strip * STRIP;

    const int tid = threadIdx.x;
    const int wv  = tid >> 6;                    // wave 0..7 = orientation
    const int l   = tid & 63;

    // ---- stage input strip rows gy0-3 .. gy0+18 (coalesced 896B/row) ----
    const float* xp = x + (size_t)(b * CH + c) * (IMG * IMG);
    {
        const int gxw = l - 1;                   // float4 index in global row
        const bool xok = (gxw >= 0) && (gxw < IMG / 4);
        for (int row = wv; row < SROWS; row += 8) {
            int gy = gy0 - 3 + row;
            f4 v = (f4)0.f;
            if (xok && gy >= 0 && gy < IMG) v = *(const f4*)(xp + gy * IMG + 4 * gxw);
            if (l < 58) *(f4*)&s_in[row * PITCH + 4 * l] = v;
        }
    }

    // ---- hoist this wave's single orientation's 49 weights (fits in regs) ----
    const float* fw = filt + ((size_t)c * NORI + wv) * 49;
    float w[49];
    #pragma unroll
    for (int k = 0; k < 49; ++k) w[k] = fw[k];

    __syncthreads();
    if (l >= 56) return;                         // 56 lanes x 4 px = 224

    const int x0 = 4 * l;
    float* op = out + ((size_t)(b * (CH * NORI) + c * NORI + wv) * IMG + gy0) * IMG + x0;

    // ---- 4 chunks of 4 output rows; rolling 4-slot input window over ky ----
    for (int chk = 0; chk < STRIP / 4; ++chk) {
        const int r0 = 4 * chk;
        float acc[4][4] = {{0,0,0,0},{0,0,0,0},{0,0,0,0},{0,0,0,0}};
        float W[4][12];

        #pragma unroll
        for (int j = 0; j < 3; ++j) READ_WIN(W[j], r0 + j);   // slots 0,1,2

        #pragma unroll
        for (int ky = 0; ky < KS; ++ky) {
            READ_WIN(W[(3 + ky) & 3], r0 + 3 + ky);  // new row -> rotating slot
            #pragma unroll
            for (int j = 0; j < 4; ++j) {            // out-row r0+j uses slot (j+ky)&3
                const float* Wr = W[(j + ky) & 3];
                #pragma unroll
                for (int kx = 0; kx < KS; ++kx) {
                    const float cw = w[ky * 7 + kx];
                    #pragma unroll
                    for (int p = 0; p < 4; ++p)
                        acc[j][p] += Wr[p + kx + 1] * cw;   // window idx 1..10
                }
            }
        }

        #pragma unroll
        for (int j = 0; j < 4; ++j) {
            f4 v; v.x = acc[j][0]; v.y = acc[j][1]; v.z = acc[j][2]; v.w = acc[j][3];
            __builtin_nontemporal_store(v, (f4*)(op + (size_t)(r0 + j) * IMG));
        }
    }
}

extern "C" void kernel_launch(void* const* d_in, const int* in_sizes, int n_in,
                              void* d_out, int out_size, void* d_ws, size_t ws_size,
                              hipStream_t stream) {
    const float* x = (const float*)d_in[0];
    const float* filt = (const float*)d_in[1];
    float* out = (float*)d_out;

    dim3 grid(14 * CH * 16);   // y-strips * channels * batch = 7168
    dim3 block(512);           // 8 waves = 8 orientations
    gabor_dw_conv<<<grid, block, 0, stream>>>(x, filt, out);
}